// Round 1
// baseline (417.473 us; speedup 1.0000x reference)
//
#include <hip/hip_runtime.h>
#include <hip/hip_bf16.h>
#include <hip/hip_fp16.h>

// Problem constants (GuidedSampler): B=32, DIM=512, H=64, W=64, K=64, DQ=3
#define BN   32
#define DIMK 512
#define HW   4096
#define KK   64
#define DQ   3
#define RR   192            // KK*DQ GEMM rows
#define NT   64             // hw columns per block
#define NBLK (HW / NT)      // 64

typedef _Float16 half8 __attribute__((ext_vector_type(8)));
typedef float    f32x4 __attribute__((ext_vector_type(4)));

// Workspace layout
#define A16_OFF    0
#define A16_BYTES  (RR * DIMK * 2)                 // 196608: W as fp16 [R][DIM]
#define DIST2_OFF  196608
#define DIST2_BYTES (BN * KK * 4)                  // 8192
#define LOSSB_OFF  (DIST2_OFF + DIST2_BYTES)       // 204800
#define KV_OFF     262144
#define KV_BYTES   ((size_t)BN * RR * HW * 2)      // 50331648 (kv as bf16)

// ---------------------------------------------------------------------------
// Kernel 1: W fp32 -> fp16, zero dist2 / per-b loss accumulators
// (ws is re-poisoned 0xAA before every timed launch -> must re-init each call)
__global__ void init_kernel(const float* __restrict__ Wsrc,
                            _Float16* __restrict__ A16,
                            float* __restrict__ dist2,
                            float* __restrict__ lossb) {
  int gid = blockIdx.x * 256 + threadIdx.x;
  if (gid < RR * DIMK) A16[gid] = (_Float16)Wsrc[gid];
  if (gid < BN * KK)   dist2[gid] = 0.f;
  if (gid < BN)        lossb[gid] = 0.f;
}

// ---------------------------------------------------------------------------
// Kernel 2: per (b, hw-tile): C[192][64] = W_f16(192x512) * f(512x64),
// store kv bf16 (STORE path), accumulate dist2[b][k] via shuffle+LDS+atomic.
// MFMA 16x16x32 f16. Fragment layouts (m89/m91-verified family):
//   A[m=lane&15][k=quad*8+j], B[k=quad*8+j][n=lane&15], C: col=lane&15,row=quad*4+reg
template <bool STORE>
__global__ __launch_bounds__(256) void gemm_dist_kernel(
    const float* __restrict__ f, const float* __restrict__ query,
    const _Float16* __restrict__ A16, __hip_bfloat16* __restrict__ kv,
    float* __restrict__ dist2) {
  // A rows padded to 40 halfs (80 B = 20 banks -> 2-way max, 16B-aligned rows)
  __shared__ __align__(16) _Float16 Alds[RR][40];
  // B transposed: [kblk][n][kin=8] -> frag read is one contiguous b128
  __shared__ __align__(16) _Float16 Blds[4][NT][8];
  __shared__ float qlds[DQ][NT];
  __shared__ float rowsum[RR];

  const int t  = threadIdx.x;
  const int w  = t >> 6;        // wave id: owns rows [48w, 48w+48) = k in [16w,16w+16)
  const int l  = t & 63;
  const int lq = l >> 4;        // quad
  const int ln = l & 15;
  const int b  = blockIdx.y;
  const int n0 = blockIdx.x * NT;

  if (t < DQ * NT) {
    int q = t / NT, n = t % NT;
    qlds[q][n] = query[((size_t)b * DQ + q) * HW + n0 + n];
  }

  f32x4 acc[3][4];
#pragma unroll
  for (int mt = 0; mt < 3; mt++)
#pragma unroll
    for (int nt = 0; nt < 4; nt++) acc[mt][nt] = (f32x4)0.f;

  const int bn  = t & 63;   // staging: column
  const int bkb = t >> 6;   // staging: k-block (8 rows each)

  for (int kk = 0; kk < DIMK / 32; kk++) {
    const int dbase = kk * 32;
    __syncthreads();
    // stage A tile 192x32 (L2-resident fp16 W)
#pragma unroll
    for (int i = 0; i < 3; i++) {
      int s = t + i * 256;
      int m = s >> 2, oct = s & 3;
      half8 av = *(const half8*)&A16[m * DIMK + dbase + oct * 8];
      *(half8*)&Alds[m][oct * 8] = av;
    }
    // stage B transposed: thread = (n, kblk); 8 coalesced 256B row reads,
    // fp32->fp16, one ds_write_b128 (stride-16B across lanes: conflict-free)
    {
      const float* fp = f + ((size_t)b * DIMK + dbase + bkb * 8) * HW + n0 + bn;
      float v[8];
#pragma unroll
      for (int j = 0; j < 8; j++) v[j] = fp[(size_t)j * HW];
      half8 hv;
#pragma unroll
      for (int j = 0; j < 8; j++) hv[j] = (_Float16)v[j];
      *(half8*)&Blds[bkb][bn][0] = hv;
    }
    __syncthreads();

    half8 af[3], bf[4];
#pragma unroll
    for (int mt = 0; mt < 3; mt++)
      af[mt] = *(const half8*)&Alds[w * 48 + mt * 16 + ln][lq * 8];
#pragma unroll
    for (int nt = 0; nt < 4; nt++)
      bf[nt] = *(const half8*)&Blds[lq][nt * 16 + ln][0];
#pragma unroll
    for (int mt = 0; mt < 3; mt++)
#pragma unroll
      for (int nt = 0; nt < 4; nt++)
        acc[mt][nt] = __builtin_amdgcn_mfma_f32_16x16x32_f16(af[mt], bf[nt],
                                                             acc[mt][nt], 0, 0, 0);
  }

  // Epilogue: kv store + per-row sq-diff partials
  float rs[3][4];
#pragma unroll
  for (int mt = 0; mt < 3; mt++)
#pragma unroll
    for (int i = 0; i < 4; i++) rs[mt][i] = 0.f;

#pragma unroll
  for (int mt = 0; mt < 3; mt++) {
#pragma unroll
    for (int i = 0; i < 4; i++) {
      int r = w * 48 + mt * 16 + lq * 4 + i;   // global row 0..191
      int q = r % 3;
#pragma unroll
      for (int nt = 0; nt < 4; nt++) {
        int n = nt * 16 + ln;
        float c = acc[mt][nt][i];
        if (STORE) kv[((size_t)b * RR + r) * HW + n0 + n] = __float2bfloat16(c);
        float d = c - qlds[q][n];
        rs[mt][i] += d * d;
      }
    }
  }
  // butterfly over low 4 lane bits (the 16 columns of a quad)
#pragma unroll
  for (int mt = 0; mt < 3; mt++)
#pragma unroll
    for (int i = 0; i < 4; i++) {
      float v = rs[mt][i];
      v += __shfl_xor(v, 1, 64);
      v += __shfl_xor(v, 2, 64);
      v += __shfl_xor(v, 4, 64);
      v += __shfl_xor(v, 8, 64);
      rs[mt][i] = v;
    }
  if (ln < 12) {
    int mt = ln >> 2, i = ln & 3;
    rowsum[w * 48 + mt * 16 + lq * 4 + i] = rs[mt][i];
  }
  __syncthreads();
  if (t < KK) {
    float v = rowsum[3 * t] + rowsum[3 * t + 1] + rowsum[3 * t + 2];
    atomicAdd(&dist2[b * KK + t], v);  // device-scope, cross-XCD safe
  }
}

// ---------------------------------------------------------------------------
// Kernel 3a (STORE path): argmin, write codes, gather kv[b][code], loss partial
__global__ __launch_bounds__(256) void gather_kernel(
    const __hip_bfloat16* __restrict__ kv, const float* __restrict__ query,
    const float* __restrict__ dist2, float* __restrict__ out,
    float* __restrict__ lossb) {
  int b = blockIdx.x, t = threadIdx.x;
  __shared__ int scode;
  __shared__ float red[4];
  if (t == 0) {
    float best = dist2[b * KK]; int bi = 0;
    for (int k = 1; k < KK; k++) {
      float v = dist2[b * KK + k];
      if (v < best) { best = v; bi = k; }   // strict < keeps first (jnp.argmin)
    }
    scode = bi;
    out[(size_t)BN * DQ * HW + b] = (float)bi;  // codes chunk, as float
  }
  __syncthreads();
  int code = scode;
  const __hip_bfloat16* src = kv + ((size_t)b * RR + code * DQ) * HW;
  const float* qp = query + (size_t)b * DQ * HW;
  float* op = out + (size_t)b * DQ * HW;
  float lsum = 0.f;
  for (int idx = t; idx < DQ * HW; idx += 256) {
    float v = __bfloat162float(src[idx]);
    op[idx] = v;
    float d = v - qp[idx];
    lsum += d * d;
  }
  for (int off = 1; off < 64; off <<= 1) lsum += __shfl_xor(lsum, off, 64);
  if ((t & 63) == 0) red[t >> 6] = lsum;
  __syncthreads();
  if (t == 0) lossb[b] = red[0] + red[1] + red[2] + red[3];
}

// ---------------------------------------------------------------------------
// Kernel 3b (fallback if ws too small): recompute selected kv from features
__global__ __launch_bounds__(256) void recompute_kernel(
    const float* __restrict__ f, const float* __restrict__ query,
    const float* __restrict__ Wsrc, const float* __restrict__ dist2,
    float* __restrict__ out, float* __restrict__ lossb) {
  int b = blockIdx.y, t = threadIdx.x;
  int hw = blockIdx.x * 256 + t;
  __shared__ int scode;
  __shared__ float red[4];
  if (t == 0) {
    float best = dist2[b * KK]; int bi = 0;
    for (int k = 1; k < KK; k++) {
      float v = dist2[b * KK + k];
      if (v < best) { best = v; bi = k; }
    }
    scode = bi;
    if (blockIdx.x == 0) out[(size_t)BN * DQ * HW + b] = (float)bi;
  }
  __syncthreads();
  int code = scode;
  const float* w0 = Wsrc + (size_t)code * DQ * DIMK;
  const float* fp = f + (size_t)b * DIMK * HW + hw;
  float a0 = 0.f, a1 = 0.f, a2 = 0.f;
  for (int d = 0; d < DIMK; d++) {
    float fv = fp[(size_t)d * HW];
    a0 += w0[d] * fv;
    a1 += w0[DIMK + d] * fv;
    a2 += w0[2 * DIMK + d] * fv;
  }
  const float* qp = query + (size_t)b * DQ * HW;
  float* op = out + (size_t)b * DQ * HW;
  op[hw] = a0; op[HW + hw] = a1; op[2 * HW + hw] = a2;
  float d0 = a0 - qp[hw], d1 = a1 - qp[HW + hw], d2 = a2 - qp[2 * HW + hw];
  float lsum = d0 * d0 + d1 * d1 + d2 * d2;
  for (int off = 1; off < 64; off <<= 1) lsum += __shfl_xor(lsum, off, 64);
  if ((t & 63) == 0) red[t >> 6] = lsum;
  __syncthreads();
  if (t == 0) atomicAdd(&lossb[b], red[0] + red[1] + red[2] + red[3]);
}

// ---------------------------------------------------------------------------
__global__ void finalize_kernel(const float* __restrict__ lossb,
                                float* __restrict__ out) {
  if (threadIdx.x == 0) {
    float s = 0.f;
    for (int b = 0; b < BN; b++) s += lossb[b];
    out[(size_t)BN * DQ * HW + BN] = s / (float)(BN * DQ * HW);
  }
}

extern "C" void kernel_launch(void* const* d_in, const int* in_sizes, int n_in,
                              void* d_out, int out_size, void* d_ws, size_t ws_size,
                              hipStream_t stream) {
  const float* f     = (const float*)d_in[0];
  const float* query = (const float*)d_in[1];
  const float* Wsrc  = (const float*)d_in[2];
  float* out = (float*)d_out;
  char*  ws  = (char*)d_ws;

  _Float16*        A16   = (_Float16*)(ws + A16_OFF);
  float*           dist2 = (float*)(ws + DIST2_OFF);
  float*           lossb = (float*)(ws + LOSSB_OFF);
  __hip_bfloat16*  kv    = (__hip_bfloat16*)(ws + KV_OFF);

  // Deterministic host-side branch (same every call -> graph-capture safe)
  const bool store = ws_size >= (size_t)KV_OFF + KV_BYTES;

  init_kernel<<<384, 256, 0, stream>>>(Wsrc, A16, dist2, lossb);
  if (store) {
    gemm_dist_kernel<true><<<dim3(NBLK, BN), 256, 0, stream>>>(f, query, A16, kv, dist2);
    gather_kernel<<<BN, 256, 0, stream>>>(kv, query, dist2, out, lossb);
  } else {
    gemm_dist_kernel<false><<<dim3(NBLK, BN), 256, 0, stream>>>(f, query, A16, nullptr, dist2);
    recompute_kernel<<<dim3(HW / 256, BN), 256, 0, stream>>>(f, query, Wsrc, dist2, out, lossb);
  }
  finalize_kernel<<<1, 64, 0, stream>>>(lossb, out);
}

// Round 2
// 380.522 us; speedup vs baseline: 1.0971x; 1.0971x over previous
//
#include <hip/hip_runtime.h>
#include <hip/hip_bf16.h>
#include <hip/hip_fp16.h>

// Problem constants (GuidedSampler): B=32, DIM=512, H=64, W=64, K=64, DQ=3
#define BN   32
#define DIMK 512
#define HW   4096
#define KK   64
#define DQ   3
#define RR   192            // KK*DQ GEMM rows
#define NT   128            // hw columns per block
#define NBLK (HW / NT)      // 32

typedef _Float16 half8  __attribute__((ext_vector_type(8)));
typedef float    f32x4  __attribute__((ext_vector_type(4)));
typedef short    short8 __attribute__((ext_vector_type(8)));

// Workspace layout
#define A16_OFF    0
#define A16_BYTES  (RR * DIMK * 2)                 // 196608: W as fp16 [R][DIM]
#define DIST2_OFF  196608
#define DIST2_BYTES (BN * KK * 4)                  // 8192
#define KV_OFF     262144
#define KV_BYTES   ((size_t)BN * RR * HW * 2)      // 50331648 (kv as bf16)

#define OUT_SEL    ((size_t)BN * DQ * HW)          // codes offset in out
#define OUT_LOSS   (OUT_SEL + BN)

// ---------------------------------------------------------------------------
// Kernel 1: W fp32 -> fp16, zero dist2 accumulator and the loss slot in out.
// (ws/out are re-poisoned 0xAA before every timed launch -> re-init each call)
__global__ void init_kernel(const float* __restrict__ Wsrc,
                            _Float16* __restrict__ A16,
                            float* __restrict__ dist2,
                            float* __restrict__ out) {
  int gid = blockIdx.x * 256 + threadIdx.x;
  if (gid < RR * DIMK) A16[gid] = (_Float16)Wsrc[gid];
  if (gid < BN * KK)   dist2[gid] = 0.f;
  if (gid == 0)        out[OUT_LOSS] = 0.f;
}

// ---------------------------------------------------------------------------
// Kernel 2: per (b, hw-tile): C[192][128] = W_f16(192x512) * f(512x128).
// Register-prefetched, LDS double-buffered (ONE barrier per K-iter; prefetch
// lands in VGPRs so no vmcnt(0) drain at the barrier). Stores kv bf16,
// accumulates dist2[b][k] via shuffle+LDS+atomic.
// MFMA 16x16x32 f16 layouts (m89/m91 family):
//   A[m=lane&15][k=quad*8+j], B[k=quad*8+j][n=lane&15], C: col=lane&15,row=quad*4+reg
template <bool STORE>
__global__ __launch_bounds__(256) void gemm_dist_kernel(
    const float* __restrict__ f, const float* __restrict__ query,
    const _Float16* __restrict__ A16, __hip_bfloat16* __restrict__ kv,
    float* __restrict__ dist2) {
  // A rows padded to 40 halfs (80 B: 16B-aligned rows, bank spread is exact)
  __shared__ __align__(16) _Float16 Alds[2][RR][40];      // 30720 B
  __shared__ __align__(16) _Float16 Blds[2][4][NT][8];    // 16384 B
  __shared__ float qlds[DQ][NT];                          // 1536 B
  __shared__ float rowsum[RR];                            // 768 B

  const int t  = threadIdx.x;
  const int w  = t >> 6;        // wave id: rows [48w, 48w+48)
  const int l  = t & 63;
  const int lq = l >> 4;        // quad
  const int ln = l & 15;
  const int b  = blockIdx.y;
  const int n0 = blockIdx.x * NT;

  for (int s = t; s < DQ * NT; s += 256) {
    int q = s / NT, n = s % NT;
    qlds[q][n] = query[((size_t)b * DQ + q) * HW + n0 + n];
  }

  f32x4 acc[3][8];
#pragma unroll
  for (int mt = 0; mt < 3; mt++)
#pragma unroll
    for (int nt = 0; nt < 8; nt++) acc[mt][nt] = (f32x4)0.f;

  // staging decomposition: thread = (column bn, k-half bkb)
  const int bn  = t & (NT - 1);   // 0..127
  const int bkb = t >> 7;         // 0..1 -> k rows [16*bkb, 16*bkb+16)

  float bpre[16];     // B prefetch regs (fp32, converted at stage time)
  half8 apre[3];      // A prefetch regs

  auto loadTile = [&](int kk) {
    const float* fp = f + ((size_t)b * DIMK + kk * 32 + bkb * 16) * HW + n0 + bn;
#pragma unroll
    for (int j = 0; j < 16; j++) bpre[j] = fp[(size_t)j * HW];
#pragma unroll
    for (int i = 0; i < 3; i++) {
      int s = t + i * 256;
      int m = s >> 2, oct = s & 3;
      apre[i] = *(const half8*)&A16[m * DIMK + kk * 32 + oct * 8];
    }
  };
  auto stageTile = [&](int buf) {
#pragma unroll
    for (int i = 0; i < 3; i++) {
      int s = t + i * 256;
      int m = s >> 2, oct = s & 3;
      *(half8*)&Alds[buf][m][oct * 8] = apre[i];
    }
    half8 h0, h1;
#pragma unroll
    for (int j = 0; j < 8; j++) { h0[j] = (_Float16)bpre[j]; h1[j] = (_Float16)bpre[8 + j]; }
    *(half8*)&Blds[buf][2 * bkb][bn][0]     = h0;
    *(half8*)&Blds[buf][2 * bkb + 1][bn][0] = h1;
  };

  loadTile(0);
  stageTile(0);
  for (int kk = 0; kk < DIMK / 32; kk++) {
    const int cur = kk & 1;
    __syncthreads();                       // buf[cur] ready; buf[cur^1] free
    if (kk < DIMK / 32 - 1) loadTile(kk + 1);   // in flight across the MFMAs

    half8 af[3], bf[8];
#pragma unroll
    for (int mt = 0; mt < 3; mt++)
      af[mt] = *(const half8*)&Alds[cur][w * 48 + mt * 16 + ln][lq * 8];
#pragma unroll
    for (int nt = 0; nt < 8; nt++)
      bf[nt] = *(const half8*)&Blds[cur][lq][nt * 16 + ln][0];
#pragma unroll
    for (int mt = 0; mt < 3; mt++)
#pragma unroll
      for (int nt = 0; nt < 8; nt++)
        acc[mt][nt] = __builtin_amdgcn_mfma_f32_16x16x32_f16(af[mt], bf[nt],
                                                             acc[mt][nt], 0, 0, 0);
    if (kk < DIMK / 32 - 1) stageTile(cur ^ 1);
  }

  // Epilogue: kv store + per-row sq-diff partials
  float rs[3][4];
#pragma unroll
  for (int mt = 0; mt < 3; mt++)
#pragma unroll
    for (int i = 0; i < 4; i++) rs[mt][i] = 0.f;

#pragma unroll
  for (int mt = 0; mt < 3; mt++) {
#pragma unroll
    for (int i = 0; i < 4; i++) {
      int r = w * 48 + mt * 16 + lq * 4 + i;   // global row 0..191
      int q = r % 3;
#pragma unroll
      for (int nt = 0; nt < 8; nt++) {
        int n = nt * 16 + ln;
        float c = acc[mt][nt][i];
        if (STORE) kv[((size_t)b * RR + r) * HW + n0 + n] = __float2bfloat16(c);
        float d = c - qlds[q][n];
        rs[mt][i] += d * d;
      }
    }
  }
  // butterfly over low 4 lane bits (sums the 16 columns within a quad)
#pragma unroll
  for (int mt = 0; mt < 3; mt++)
#pragma unroll
    for (int i = 0; i < 4; i++) {
      float v = rs[mt][i];
      v += __shfl_xor(v, 1, 64);
      v += __shfl_xor(v, 2, 64);
      v += __shfl_xor(v, 4, 64);
      v += __shfl_xor(v, 8, 64);
      rs[mt][i] = v;
    }
  if (ln < 12) {
    int mt = ln >> 2, i = ln & 3;
    rowsum[w * 48 + mt * 16 + lq * 4 + i] = rs[mt][i];
  }
  __syncthreads();
  if (t < KK) {
    float v = rowsum[3 * t] + rowsum[3 * t + 1] + rowsum[3 * t + 2];
    atomicAdd(&dist2[b * KK + t], v);  // device-scope, cross-XCD safe
  }
}

// ---------------------------------------------------------------------------
// Kernel 3a (STORE path): argmin, write codes, gather kv[b][code], loss atomic
__global__ __launch_bounds__(256) void gather_kernel(
    const __hip_bfloat16* __restrict__ kv, const float* __restrict__ query,
    const float* __restrict__ dist2, float* __restrict__ out) {
  int b = blockIdx.x, t = threadIdx.x;
  __shared__ int scode;
  __shared__ float red[4];
  if (t == 0) {
    float best = dist2[b * KK]; int bi = 0;
    for (int k = 1; k < KK; k++) {
      float v = dist2[b * KK + k];
      if (v < best) { best = v; bi = k; }   // strict < keeps first (jnp.argmin)
    }
    scode = bi;
    out[OUT_SEL + b] = (float)bi;           // codes chunk, as float
  }
  __syncthreads();
  int code = scode;
  const short8* src = (const short8*)(kv + ((size_t)b * RR + code * DQ) * HW);
  const f32x4*  qp  = (const f32x4*)(query + (size_t)b * DQ * HW);
  f32x4*        op  = (f32x4*)(out + (size_t)b * DQ * HW);
  float lsum = 0.f;
  for (int c = t; c < DQ * HW / 8; c += 256) {   // 1536 short8 chunks
    short8 v = src[c];
    f32x4 o0, o1;
#pragma unroll
    for (int j = 0; j < 4; j++) {
      unsigned u0 = ((unsigned)(unsigned short)v[j]) << 16;
      unsigned u1 = ((unsigned)(unsigned short)v[4 + j]) << 16;
      o0[j] = __builtin_bit_cast(float, u0);
      o1[j] = __builtin_bit_cast(float, u1);
    }
    f32x4 q0 = qp[2 * c], q1 = qp[2 * c + 1];
    op[2 * c] = o0; op[2 * c + 1] = o1;
#pragma unroll
    for (int j = 0; j < 4; j++) {
      float d0 = o0[j] - q0[j], d1 = o1[j] - q1[j];
      lsum += d0 * d0 + d1 * d1;
    }
  }
  for (int off = 1; off < 64; off <<= 1) lsum += __shfl_xor(lsum, off, 64);
  if ((t & 63) == 0) red[t >> 6] = lsum;
  __syncthreads();
  if (t == 0)
    atomicAdd(&out[OUT_LOSS],
              (red[0] + red[1] + red[2] + red[3]) * (1.f / (float)(BN * DQ * HW)));
}

// ---------------------------------------------------------------------------
// Kernel 3b (fallback if ws too small): recompute selected kv from features
__global__ __launch_bounds__(256) void recompute_kernel(
    const float* __restrict__ f, const float* __restrict__ query,
    const float* __restrict__ Wsrc, const float* __restrict__ dist2,
    float* __restrict__ out) {
  int b = blockIdx.y, t = threadIdx.x;
  int hw = blockIdx.x * 256 + t;
  __shared__ int scode;
  __shared__ float red[4];
  if (t == 0) {
    float best = dist2[b * KK]; int bi = 0;
    for (int k = 1; k < KK; k++) {
      float v = dist2[b * KK + k];
      if (v < best) { best = v; bi = k; }
    }
    scode = bi;
    if (blockIdx.x == 0) out[OUT_SEL + b] = (float)bi;
  }
  __syncthreads();
  int code = scode;
  const float* w0 = Wsrc + (size_t)code * DQ * DIMK;
  const float* fp = f + (size_t)b * DIMK * HW + hw;
  float a0 = 0.f, a1 = 0.f, a2 = 0.f;
  for (int d = 0; d < DIMK; d++) {
    float fv = fp[(size_t)d * HW];
    a0 += w0[d] * fv;
    a1 += w0[DIMK + d] * fv;
    a2 += w0[2 * DIMK + d] * fv;
  }
  const float* qp = query + (size_t)b * DQ * HW;
  float* op = out + (size_t)b * DQ * HW;
  op[hw] = a0; op[HW + hw] = a1; op[2 * HW + hw] = a2;
  float d0 = a0 - qp[hw], d1 = a1 - qp[HW + hw], d2 = a2 - qp[2 * HW + hw];
  float lsum = d0 * d0 + d1 * d1 + d2 * d2;
  for (int off = 1; off < 64; off <<= 1) lsum += __shfl_xor(lsum, off, 64);
  if ((t & 63) == 0) red[t >> 6] = lsum;
  __syncthreads();
  if (t == 0)
    atomicAdd(&out[OUT_LOSS],
              (red[0] + red[1] + red[2] + red[3]) * (1.f / (float)(BN * DQ * HW)));
}

extern "C" void kernel_launch(void* const* d_in, const int* in_sizes, int n_in,
                              void* d_out, int out_size, void* d_ws, size_t ws_size,
                              hipStream_t stream) {
  const float* f     = (const float*)d_in[0];
  const float* query = (const float*)d_in[1];
  const float* Wsrc  = (const float*)d_in[2];
  float* out = (float*)d_out;
  char*  ws  = (char*)d_ws;

  _Float16*        A16   = (_Float16*)(ws + A16_OFF);
  float*           dist2 = (float*)(ws + DIST2_OFF);
  __hip_bfloat16*  kv    = (__hip_bfloat16*)(ws + KV_OFF);

  // Deterministic host-side branch (same every call -> graph-capture safe)
  const bool store = ws_size >= (size_t)KV_OFF + KV_BYTES;

  init_kernel<<<384, 256, 0, stream>>>(Wsrc, A16, dist2, out);
  if (store) {
    gemm_dist_kernel<true><<<dim3(NBLK, BN), 256, 0, stream>>>(f, query, A16, kv, dist2);
    gather_kernel<<<BN, 256, 0, stream>>>(kv, query, dist2, out);
  } else {
    gemm_dist_kernel<false><<<dim3(NBLK, BN), 256, 0, stream>>>(f, query, A16, nullptr, dist2);
    recompute_kernel<<<dim3(HW / 256, BN), 256, 0, stream>>>(f, query, Wsrc, dist2, out);
  }
}